// Round 14
// baseline (366.776 us; speedup 1.0000x reference)
//
#include <hip/hip_runtime.h>
#include <hip/hip_bf16.h>

#define NN 50000
#define EE 400000
#define QSCALE 131072.0f   // 2^17 fixed-point scale for packed histogram
#define SCAN_CHUNK 2048
#define CAP 64             // static bucket capacity (max degree ~40 for this graph)
#define ACCBLK 12500       // accumulate grid: NN/4 waves-per-block=4

typedef short bf16x8 __attribute__((ext_vector_type(8)));
typedef float f32x4 __attribute__((ext_vector_type(4)));
typedef float f32x4v __attribute__((ext_vector_type(4)));
typedef float f32x2v __attribute__((ext_vector_type(2)));

__device__ inline unsigned bf16pair(float a, float b) {
    unsigned ua = __float_as_uint(a), ub = __float_as_uint(b);
    ua = (ua + 0x7FFFu + ((ua >> 16) & 1u)) >> 16;
    ub = (ub + 0x7FFFu + ((ub >> 16) & 1u)) >> 16;
    return ua | (ub << 16);
}

// ---------------- prep: a-folds (block 0) + W transposes + hist zero ----------------
__global__ void prep(const float* __restrict__ W_node, const float* __restrict__ W_edge,
                     const float* __restrict__ a_node, const float* __restrict__ a_edge,
                     float* wn_a1, float* wn_a2, float* wn_e1, float* we_a2,
                     unsigned short* __restrict__ Wt_node, unsigned short* __restrict__ Wt_edge,
                     unsigned long long* __restrict__ hist) {
    int t = threadIdx.x;
    if (blockIdx.x == 0) {
        if (t < 256) {
            float x1 = 0.f, x2 = 0.f, x3 = 0.f;
            for (int j = 0; j < 128; ++j) {
                float w = W_node[t * 128 + j];
                x1 += w * a_node[j];
                x2 += w * a_node[128 + j];
                x3 += w * a_edge[j];
            }
            wn_a1[t] = x1; wn_a2[t] = x2; wn_e1[t] = x3;
        }
        if (t < 128) {
            float x = 0.f;
            for (int j = 0; j < 128; ++j) x += W_edge[t * 128 + j] * a_edge[128 + j];
            we_a2[t] = x;
        }
    }
    int gid = blockIdx.x * blockDim.x + t;
    int nth = gridDim.x * blockDim.x;
    for (int idx = gid; idx < 256 * 128; idx += nth) {
        int r = idx >> 7, c = idx & 127;
        unsigned u = __float_as_uint(W_node[idx]);
        u = (u + 0x7FFFu + ((u >> 16) & 1u)) >> 16;
        Wt_node[c * 256 + r] = (unsigned short)u;
    }
    for (int idx = gid; idx < 128 * 128; idx += nth) {
        int r = idx >> 7, c = idx & 127;
        unsigned u = __float_as_uint(W_edge[idx]);
        u = (u + 0x7FFFu + ((u >> 16) & 1u)) >> 16;
        Wt_edge[c * 128 + r] = (unsigned short)u;
    }
    for (int idx = gid; idx < NN; idx += nth) hist[idx] = 0ULL;
}

// ---------------- fused MFMA bf16 GEMM (h + e + 4 scalar dots), full-line hev writes ----------------
__global__ __launch_bounds__(256) void gemm_fused(const float* __restrict__ NF,
                                                  const float* __restrict__ EF,
                                                  const unsigned short* __restrict__ WtN,
                                                  const unsigned short* __restrict__ WtE,
                                                  const float* __restrict__ w1,
                                                  const float* __restrict__ w2,
                                                  const float* __restrict__ w3,
                                                  const float* __restrict__ w4,
                                                  unsigned* __restrict__ hevu,
                                                  float* __restrict__ s1, float* __restrict__ s2,
                                                  float* __restrict__ t1, float* __restrict__ t2e,
                                                  int M) {
    int t = threadIdx.x;
    int wv = t >> 6, l = t & 63;
    int rl = l & 15, kg = l >> 4;
    int wrow0 = blockIdx.x * 64 + wv * 16;
    int gr = wrow0 + rl;
    int ar = gr < M ? gr : M - 1;
    const float* ArowN = NF + (size_t)ar * 256;
    const float* ArowE = EF + (size_t)ar * 128;
    f32x4 accH[8], accE[8];
#pragma unroll
    for (int i = 0; i < 8; ++i) { accH[i] = (f32x4){0.f,0.f,0.f,0.f}; accE[i] = (f32x4){0.f,0.f,0.f,0.f}; }
    float p1 = 0.f, p2 = 0.f, p3 = 0.f, p4 = 0.f;
    // ---- node part: K=256 ----
    for (int k0 = 0; k0 < 256; k0 += 32) {
        int kb = k0 + kg * 8;
        f32x4v alo = __builtin_nontemporal_load(reinterpret_cast<const f32x4v*>(ArowN + kb));
        f32x4v ahi = __builtin_nontemporal_load(reinterpret_cast<const f32x4v*>(ArowN + kb + 4));
        union { unsigned u[4]; bf16x8 v; } af;
        af.u[0] = bf16pair(alo.x, alo.y);
        af.u[1] = bf16pair(alo.z, alo.w);
        af.u[2] = bf16pair(ahi.x, ahi.y);
        af.u[3] = bf16pair(ahi.z, ahi.w);
        {
            float4 wl = *reinterpret_cast<const float4*>(w1 + kb);
            float4 wh = *reinterpret_cast<const float4*>(w1 + kb + 4);
            p1 += alo.x*wl.x + alo.y*wl.y + alo.z*wl.z + alo.w*wl.w
                + ahi.x*wh.x + ahi.y*wh.y + ahi.z*wh.z + ahi.w*wh.w;
        }
        {
            float4 wl = *reinterpret_cast<const float4*>(w2 + kb);
            float4 wh = *reinterpret_cast<const float4*>(w2 + kb + 4);
            p2 += alo.x*wl.x + alo.y*wl.y + alo.z*wl.z + alo.w*wl.w
                + ahi.x*wh.x + ahi.y*wh.y + ahi.z*wh.z + ahi.w*wh.w;
        }
        {
            float4 wl = *reinterpret_cast<const float4*>(w3 + kb);
            float4 wh = *reinterpret_cast<const float4*>(w3 + kb + 4);
            p3 += alo.x*wl.x + alo.y*wl.y + alo.z*wl.z + alo.w*wl.w
                + ahi.x*wh.x + ahi.y*wh.y + ahi.z*wh.z + ahi.w*wh.w;
        }
#pragma unroll
        for (int nt = 0; nt < 8; ++nt) {
            union { unsigned u[4]; bf16x8 v; } bf;
            const unsigned* bp = reinterpret_cast<const unsigned*>(WtN + (size_t)(rl + 16*nt) * 256 + kb);
            bf.u[0] = bp[0]; bf.u[1] = bp[1]; bf.u[2] = bp[2]; bf.u[3] = bp[3];
            accH[nt] = __builtin_amdgcn_mfma_f32_16x16x32_bf16(af.v, bf.v, accH[nt], 0, 0, 0);
        }
    }
    // ---- edge part: K=128 ----
    for (int k0 = 0; k0 < 128; k0 += 32) {
        int kb = k0 + kg * 8;
        f32x4v alo = __builtin_nontemporal_load(reinterpret_cast<const f32x4v*>(ArowE + kb));
        f32x4v ahi = __builtin_nontemporal_load(reinterpret_cast<const f32x4v*>(ArowE + kb + 4));
        union { unsigned u[4]; bf16x8 v; } af;
        af.u[0] = bf16pair(alo.x, alo.y);
        af.u[1] = bf16pair(alo.z, alo.w);
        af.u[2] = bf16pair(ahi.x, ahi.y);
        af.u[3] = bf16pair(ahi.z, ahi.w);
        {
            float4 wl = *reinterpret_cast<const float4*>(w4 + kb);
            float4 wh = *reinterpret_cast<const float4*>(w4 + kb + 4);
            p4 += alo.x*wl.x + alo.y*wl.y + alo.z*wl.z + alo.w*wl.w
                + ahi.x*wh.x + ahi.y*wh.y + ahi.z*wh.z + ahi.w*wh.w;
        }
#pragma unroll
        for (int nt = 0; nt < 8; ++nt) {
            union { unsigned u[4]; bf16x8 v; } bf;
            const unsigned* bp = reinterpret_cast<const unsigned*>(WtE + (size_t)(rl + 16*nt) * 128 + kb);
            bf.u[0] = bp[0]; bf.u[1] = bp[1]; bf.u[2] = bp[2]; bf.u[3] = bp[3];
            accE[nt] = __builtin_amdgcn_mfma_f32_16x16x32_bf16(af.v, bf.v, accE[nt], 0, 0, 0);
        }
    }
    // fused scalar outputs
    p1 += __shfl_xor(p1, 16); p1 += __shfl_xor(p1, 32);
    p2 += __shfl_xor(p2, 16); p2 += __shfl_xor(p2, 32);
    p3 += __shfl_xor(p3, 16); p3 += __shfl_xor(p3, 32);
    p4 += __shfl_xor(p4, 16); p4 += __shfl_xor(p4, 32);
    if (l < 16 && gr < M) { s1[gr] = p1; s2[gr] = p2; t1[gr] = p3; t2e[gr] = p4; }
    // epilogue: full uint2 (h-pair, e-pair) writes
#pragma unroll
    for (int nt = 0; nt < 8; ++nt) {
#pragma unroll
        for (int reg = 0; reg < 4; ++reg) {
            float hm = accH[nt][reg];
            float ho = __shfl_xor(hm, 1);
            float em = accE[nt][reg];
            float eo = __shfl_xor(em, 1);
            int orow = wrow0 + kg * 4 + reg;
            if (orow < M) {
                int col = rl + 16 * nt;
                if (!(l & 1)) {
                    if (reg < 2) {
                        uint2 wv2 = { bf16pair(hm, ho), bf16pair(em, eo) };
                        *reinterpret_cast<uint2*>(hevu + (size_t)orow * 128 + col) = wv2;
                    }
                } else {
                    if (reg >= 2) {
                        uint2 wv2 = { bf16pair(ho, hm), bf16pair(eo, em) };
                        *reinterpret_cast<uint2*>(hevu + (size_t)orow * 128 + (col - 1)) = wv2;
                    }
                }
            }
        }
    }
}

// ---------------- per-edge scalar t2e for rows [NN, EE) ----------------
__global__ void edge_scalar_tail(const float* __restrict__ EF, const float* __restrict__ w,
                                 float* __restrict__ t2e) {
    int wave = NN + (int)((blockIdx.x * (size_t)blockDim.x + threadIdx.x) >> 6);
    int lane = threadIdx.x & 63;
    if (wave >= EE) return;
    f32x2v v = __builtin_nontemporal_load(reinterpret_cast<const f32x2v*>(EF + (size_t)wave * 128 + lane * 2));
    float a = v.x * w[lane * 2] + v.y * w[lane * 2 + 1];
    for (int off = 32; off; off >>= 1) a += __shfl_down(a, off);
    if (lane == 0) t2e[wave] = a;
}

// ---------------- attention: 1 packed u64 atomic + direct static-bucket meta scatter ----------------
// meta[s*CAP + rank] = { d_bits, i_bits, na, ea }  (raw attention values; normalized later)
__global__ void attention(const int* __restrict__ edges, const float* __restrict__ s1,
                          const float* __restrict__ s2, const float* __restrict__ t1,
                          const float* __restrict__ t2e, unsigned long long* __restrict__ hist,
                          float4* __restrict__ meta) {
    int i = blockIdx.x * blockDim.x + threadIdx.x;
    if (i >= 2 * EE) return;
    int s, d, j;
    if (i < EE) { j = i; int2 p = *reinterpret_cast<const int2*>(edges + 2 * j); s = p.x; d = p.y; }
    else        { j = i - EE; int2 p = *reinterpret_cast<const int2*>(edges + 2 * j); s = p.y; d = p.x; }
    float xn = s1[s] + s2[d];
    xn = xn >= 0.f ? xn : 0.2f * xn;
    xn = fminf(fmaxf(xn, -2.f), 2.f);
    float na = __expf(xn);
    float xe = t1[s] + t2e[j];
    xe = xe >= 0.f ? xe : 0.2f * xe;
    xe = fminf(fmaxf(xe, -2.f), 2.f);
    float ea = __expf(xe);
    unsigned qn = __float2uint_rn(na * QSCALE);
    unsigned qe = __float2uint_rn(ea * QSCALE);
    unsigned long long pk = (1ULL << 56) | ((unsigned long long)qn << 28) | (unsigned long long)qe;
    unsigned long long old = atomicAdd(&hist[s], pk);
    int rank = (int)(old >> 56) & (CAP - 1);
    meta[(size_t)s * CAP + rank] = make_float4(__int_as_float(d), __int_as_float(i), na, ea);
}

// ---------------- unpack hist -> reciprocal sums + counts + per-chunk count sums ----------------
__global__ void reduce_unpack(const unsigned long long* __restrict__ hist, float* __restrict__ rns,
                              float* __restrict__ res, int* __restrict__ counts,
                              int* __restrict__ bsums) {
    __shared__ int sdata[256];
    int b = blockIdx.x, t = threadIdx.x;
    int base = b * SCAN_CHUNK;
    int csum = 0;
    for (int j = 0; j < 8; ++j) {
        int idx = base + j * 256 + t;
        if (idx < NN) {
            unsigned long long h = hist[idx];
            int c = (int)(h >> 56);
            counts[idx] = c;
            float qn = (float)((h >> 28) & 0x0FFFFFFFULL);
            float qe = (float)(h & 0x0FFFFFFFULL);
            rns[idx] = QSCALE / qn;
            res[idx] = QSCALE / qe;
            csum += c;
        }
    }
    sdata[t] = csum; __syncthreads();
    for (int off = 128; off; off >>= 1) { if (t < off) sdata[t] += sdata[t + off]; __syncthreads(); }
    if (t == 0) bsums[b] = sdata[0];
}

// ---------------- final scan: offsets + position->node map g ----------------
__global__ void scan_final(const int* __restrict__ counts, const int* __restrict__ bsums,
                           int* __restrict__ offsets, int* __restrict__ g) {
    __shared__ int sdata[256];
    int b = blockIdx.x, t = threadIdx.x;
    int base = b * SCAN_CHUNK + t * 8;
    int bbase = 0;
    for (int q = 0; q < b; ++q) bbase += bsums[q];
    int loc[8]; int s = 0;
    for (int j = 0; j < 8; ++j) { int idx = base + j; int v = (idx < NN) ? counts[idx] : 0; loc[j] = v; s += v; }
    sdata[t] = s; __syncthreads();
    for (int off = 1; off < 256; off <<= 1) {
        int v = (t >= off) ? sdata[t - off] : 0;
        __syncthreads();
        sdata[t] += v;
        __syncthreads();
    }
    int run = sdata[t] - s + bbase;
    for (int j = 0; j < 8; ++j) {
        int idx = base + j;
        if (idx < NN) {
            offsets[idx] = run;
            for (int k = 0; k < loc[j]; ++k) g[run + k] = idx;
            run += loc[j];
        }
    }
}

// ---------------- accumulate: normalization folded in + variance partials, quarter-wave ----------------
__global__ void accumulate(const float4* __restrict__ meta, const int* __restrict__ counts,
                           const int* __restrict__ g, const float* __restrict__ rns,
                           const float* __restrict__ res, const uint4* __restrict__ hev,
                           float* __restrict__ node_out, float* __restrict__ edge_out,
                           double* __restrict__ partials) {
    int wave = (int)((blockIdx.x * (size_t)blockDim.x + threadIdx.x) >> 6);
    int lane = threadIdx.x & 63;
    int q = lane >> 4, sl = lane & 15;
    const float4* mb = meta + (size_t)wave * CAP;
    int c = counts[wave];
    float aH[8] = {}, aE[8] = {};
    double v0 = 0.0, v1 = 0.0, v2 = 0.0, v3 = 0.0;
    float4 z = make_float4(0.f, 0.f, 0.f, 0.f);
    uint4 zu = make_uint4(0u, 0u, 0u, 0u);
    int np = (c + 3) >> 2;
    // preamble: edge A (k=0), meta for edge B (k=1)
    int eA = q;
    float4 mA = (eA < c) ? mb[eA] : z;
    uint4 vAa = zu, vAb = zu;
    if (eA < c) {
        const uint4* r = hev + (size_t)__float_as_int(mA.x) * 32 + sl * 2;
        vAa = r[0]; vAb = r[1];
    }
    int loA = g[__float_as_int(mA.y)];
    float fnA = mA.z * rns[loA];
    float feA = mA.w * res[loA];
    int eB = 4 + q;
    float4 mB = (eB < c) ? mb[eB] : z;
    for (int k = 0; k < np; ++k) {
        int eC = 4 * (k + 2) + q;
        float4 mC = (eC < c) ? mb[eC] : z;
        int eBv = 4 * (k + 1) + q;
        uint4 vBa = zu, vBb = zu;
        if (eBv < c) {
            const uint4* r = hev + (size_t)__float_as_int(mB.x) * 32 + sl * 2;
            vBa = r[0]; vBb = r[1];
        }
        int loB = g[__float_as_int(mB.y)];
        float fnB = mB.z * rns[loB];
        float feB = mB.w * res[loB];
        // FMA edge A
        aH[0] += __uint_as_float(vAa.x << 16) * fnA;
        aH[1] += __uint_as_float(vAa.x & 0xFFFF0000u) * fnA;
        aE[0] += __uint_as_float(vAa.y << 16) * feA;
        aE[1] += __uint_as_float(vAa.y & 0xFFFF0000u) * feA;
        aH[2] += __uint_as_float(vAa.z << 16) * fnA;
        aH[3] += __uint_as_float(vAa.z & 0xFFFF0000u) * fnA;
        aE[2] += __uint_as_float(vAa.w << 16) * feA;
        aE[3] += __uint_as_float(vAa.w & 0xFFFF0000u) * feA;
        aH[4] += __uint_as_float(vAb.x << 16) * fnA;
        aH[5] += __uint_as_float(vAb.x & 0xFFFF0000u) * fnA;
        aE[4] += __uint_as_float(vAb.y << 16) * feA;
        aE[5] += __uint_as_float(vAb.y & 0xFFFF0000u) * feA;
        aH[6] += __uint_as_float(vAb.z << 16) * fnA;
        aH[7] += __uint_as_float(vAb.z & 0xFFFF0000u) * fnA;
        aE[6] += __uint_as_float(vAb.w << 16) * feA;
        aE[7] += __uint_as_float(vAb.w & 0xFFFF0000u) * feA;
        if (sl == 0) {
            v0 += (double)fnA; v1 += (double)fnA * fnA;
            v2 += (double)feA; v3 += (double)feA * feA;
        }
        mA = mB; vAa = vBa; vAb = vBb; fnA = fnB; feA = feB; mB = mC;
    }
#pragma unroll
    for (int x = 0; x < 8; ++x) {
        aH[x] += __shfl_xor(aH[x], 16); aH[x] += __shfl_xor(aH[x], 32);
        aE[x] += __shfl_xor(aE[x], 16); aE[x] += __shfl_xor(aE[x], 32);
    }
    if (q == 0) {
        f32x4v h0 = { aH[0], aH[1], aH[2], aH[3] };
        f32x4v h1 = { aH[4], aH[5], aH[6], aH[7] };
        f32x4v e0v = { aE[0], aE[1], aE[2], aE[3] };
        f32x4v e1v = { aE[4], aE[5], aE[6], aE[7] };
        __builtin_nontemporal_store(h0, reinterpret_cast<f32x4v*>(node_out + (size_t)wave * 128 + sl * 8));
        __builtin_nontemporal_store(h1, reinterpret_cast<f32x4v*>(node_out + (size_t)wave * 128 + sl * 8 + 4));
        __builtin_nontemporal_store(e0v, reinterpret_cast<f32x4v*>(edge_out + (size_t)wave * 128 + sl * 8));
        __builtin_nontemporal_store(e1v, reinterpret_cast<f32x4v*>(edge_out + (size_t)wave * 128 + sl * 8 + 4));
    }
    // variance partials: sl==0 lanes (0,16,32,48) hold moments; reduce within wave then block
    v0 += __shfl_xor(v0, 16); v0 += __shfl_xor(v0, 32);
    v1 += __shfl_xor(v1, 16); v1 += __shfl_xor(v1, 32);
    v2 += __shfl_xor(v2, 16); v2 += __shfl_xor(v2, 32);
    v3 += __shfl_xor(v3, 16); v3 += __shfl_xor(v3, 32);
    __shared__ double sd[4][4];
    int wv = threadIdx.x >> 6;
    if (lane == 0) { sd[0][wv] = v0; sd[1][wv] = v1; sd[2][wv] = v2; sd[3][wv] = v3; }
    __syncthreads();
    if (threadIdx.x < 4) {
        double x = sd[threadIdx.x][0] + sd[threadIdx.x][1] + sd[threadIdx.x][2] + sd[threadIdx.x][3];
        partials[(size_t)blockIdx.x * 4 + threadIdx.x] = x;
    }
}

// ---------------- finalize variance: reduce block partials ----------------
__global__ void finalize_var(const double* __restrict__ partials, float* __restrict__ out_var) {
    __shared__ double sd[4][4];
    int t = threadIdx.x;
    int q = t & 3, chunk = t >> 2;   // 64 chunks per moment
    double x = 0.0;
    for (int b = chunk; b < ACCBLK; b += 64) x += partials[(size_t)b * 4 + q];
    int lane = t & 63, wv = t >> 6;
    for (int off = 32; off >= 4; off >>= 1) x += __shfl_xor(x, off);
    if (lane < 4) sd[lane][wv] = x;
    __syncthreads();
    if (t == 0) {
        double a0 = sd[0][0] + sd[0][1] + sd[0][2] + sd[0][3];
        double a1 = sd[1][0] + sd[1][1] + sd[1][2] + sd[1][3];
        double a2 = sd[2][0] + sd[2][1] + sd[2][2] + sd[2][3];
        double a3 = sd[3][0] + sd[3][1] + sd[3][2] + sd[3][3];
        double M = 2.0 * EE;
        out_var[0] = (float)((a1 - a0 * a0 / M) / (M - 1.0));
        out_var[1] = (float)((a3 - a2 * a2 / M) / (M - 1.0));
    }
}

extern "C" void kernel_launch(void* const* d_in, const int* in_sizes, int n_in,
                              void* d_out, int out_size, void* d_ws, size_t ws_size,
                              hipStream_t stream) {
    const float* node_fts = (const float*)d_in[0];
    const float* edge_fts = (const float*)d_in[1];
    const int*   edges    = (const int*)d_in[2];
    const float* W_node   = (const float*)d_in[3];
    const float* W_edge   = (const float*)d_in[4];
    const float* a_node   = (const float*)d_in[5];
    const float* a_edge   = (const float*)d_in[6];
    float* out = (float*)d_out;

    char* w = (char*)d_ws;
    auto alloc = [&](size_t bytes) -> void* {
        void* p = (void*)w;
        w += (bytes + 255) & ~(size_t)255;
        return p;
    };
    unsigned* hevu = (unsigned*)alloc((size_t)NN * 512);        // bf16 interleaved h/e rows
    float4* meta = (float4*)alloc((size_t)NN * CAP * 16);       // static buckets (51.2 MB)
    float* s1    = (float*)alloc(NN * 4);
    float* s2    = (float*)alloc(NN * 4);
    float* t1    = (float*)alloc(NN * 4);
    float* t2e   = (float*)alloc(EE * 4);
    int*   offsets = (int*)alloc((NN + 1) * 4);
    int*   g       = (int*)alloc((size_t)2 * EE * 4);
    int*   bsums   = (int*)alloc(64 * 4);
    float* wn_a1 = (float*)alloc(256 * 4);
    float* wn_a2 = (float*)alloc(256 * 4);
    float* wn_e1 = (float*)alloc(256 * 4);
    float* we_a2 = (float*)alloc(128 * 4);
    unsigned short* Wt_node = (unsigned short*)alloc(256 * 128 * 2);
    unsigned short* Wt_edge = (unsigned short*)alloc(128 * 128 * 2);
    float* rns    = (float*)alloc(NN * 4);
    float* res    = (float*)alloc(NN * 4);
    int*   counts = (int*)alloc(NN * 4);
    double* partials = (double*)alloc((size_t)ACCBLK * 4 * 8);
    unsigned long long* hist = (unsigned long long*)alloc((size_t)NN * 8);

    prep<<<64, 256, 0, stream>>>(W_node, W_edge, a_node, a_edge, wn_a1, wn_a2, wn_e1, we_a2,
                                 Wt_node, Wt_edge, hist);

    const int gemm_grid = (NN + 63) / 64;  // 782
    gemm_fused<<<gemm_grid, 256, 0, stream>>>(node_fts, edge_fts, Wt_node, Wt_edge,
                                              wn_a1, wn_a2, wn_e1, we_a2,
                                              hevu, s1, s2, t1, t2e, NN);

    edge_scalar_tail<<<((EE - NN) + 3) / 4, 256, 0, stream>>>(edge_fts, we_a2, t2e);

    attention<<<(2 * EE + 255) / 256, 256, 0, stream>>>(edges, s1, s2, t1, t2e, hist, meta);

    const int nscan = (NN + SCAN_CHUNK - 1) / SCAN_CHUNK;  // 25
    reduce_unpack<<<nscan, 256, 0, stream>>>(hist, rns, res, counts, bsums);
    scan_final<<<nscan, 256, 0, stream>>>(counts, bsums, offsets, g);

    accumulate<<<ACCBLK, 256, 0, stream>>>(meta, counts, g, rns, res, (const uint4*)hevu,
                                           out, out + (size_t)NN * 128, partials);

    finalize_var<<<1, 256, 0, stream>>>(partials, out + (size_t)2 * NN * 128);
}

// Round 15
// 306.504 us; speedup vs baseline: 1.1966x; 1.1966x over previous
//
#include <hip/hip_runtime.h>
#include <hip/hip_bf16.h>

#define NN 50000
#define EE 400000
#define QSCALE 131072.0f   // 2^17 fixed-point scale for packed histogram
#define SCAN_CHUNK 2048
#define CAP 64             // static bucket capacity (max degree ~40 for this graph)
#define NVBLK 1040         // normalize_slots grid (grid-stride); partials, no atomics

typedef short bf16x8 __attribute__((ext_vector_type(8)));
typedef float f32x4 __attribute__((ext_vector_type(4)));
typedef float f32x4v __attribute__((ext_vector_type(4)));
typedef float f32x2v __attribute__((ext_vector_type(2)));

__device__ inline unsigned bf16pair(float a, float b) {
    unsigned ua = __float_as_uint(a), ub = __float_as_uint(b);
    ua = (ua + 0x7FFFu + ((ua >> 16) & 1u)) >> 16;
    ub = (ub + 0x7FFFu + ((ub >> 16) & 1u)) >> 16;
    return ua | (ub << 16);
}

// ---------------- prep: a-folds (block 0) + W transposes + hist zero ----------------
__global__ void prep(const float* __restrict__ W_node, const float* __restrict__ W_edge,
                     const float* __restrict__ a_node, const float* __restrict__ a_edge,
                     float* wn_a1, float* wn_a2, float* wn_e1, float* we_a2,
                     unsigned short* __restrict__ Wt_node, unsigned short* __restrict__ Wt_edge,
                     unsigned long long* __restrict__ hist) {
    int t = threadIdx.x;
    if (blockIdx.x == 0) {
        if (t < 256) {
            float x1 = 0.f, x2 = 0.f, x3 = 0.f;
            for (int j = 0; j < 128; ++j) {
                float w = W_node[t * 128 + j];
                x1 += w * a_node[j];
                x2 += w * a_node[128 + j];
                x3 += w * a_edge[j];
            }
            wn_a1[t] = x1; wn_a2[t] = x2; wn_e1[t] = x3;
        }
        if (t < 128) {
            float x = 0.f;
            for (int j = 0; j < 128; ++j) x += W_edge[t * 128 + j] * a_edge[128 + j];
            we_a2[t] = x;
        }
    }
    int gid = blockIdx.x * blockDim.x + t;
    int nth = gridDim.x * blockDim.x;
    for (int idx = gid; idx < 256 * 128; idx += nth) {
        int r = idx >> 7, c = idx & 127;
        unsigned u = __float_as_uint(W_node[idx]);
        u = (u + 0x7FFFu + ((u >> 16) & 1u)) >> 16;
        Wt_node[c * 256 + r] = (unsigned short)u;
    }
    for (int idx = gid; idx < 128 * 128; idx += nth) {
        int r = idx >> 7, c = idx & 127;
        unsigned u = __float_as_uint(W_edge[idx]);
        u = (u + 0x7FFFu + ((u >> 16) & 1u)) >> 16;
        Wt_edge[c * 128 + r] = (unsigned short)u;
    }
    for (int idx = gid; idx < NN; idx += nth) hist[idx] = 0ULL;
}

// ---------------- fused MFMA bf16 GEMM (h + e + 4 scalar dots), full-line hev writes ----------------
__global__ __launch_bounds__(256) void gemm_fused(const float* __restrict__ NF,
                                                  const float* __restrict__ EF,
                                                  const unsigned short* __restrict__ WtN,
                                                  const unsigned short* __restrict__ WtE,
                                                  const float* __restrict__ w1,
                                                  const float* __restrict__ w2,
                                                  const float* __restrict__ w3,
                                                  const float* __restrict__ w4,
                                                  unsigned* __restrict__ hevu,
                                                  float* __restrict__ s1, float* __restrict__ s2,
                                                  float* __restrict__ t1, float* __restrict__ t2e,
                                                  int M) {
    int t = threadIdx.x;
    int wv = t >> 6, l = t & 63;
    int rl = l & 15, kg = l >> 4;
    int wrow0 = blockIdx.x * 64 + wv * 16;
    int gr = wrow0 + rl;
    int ar = gr < M ? gr : M - 1;
    const float* ArowN = NF + (size_t)ar * 256;
    const float* ArowE = EF + (size_t)ar * 128;
    f32x4 accH[8], accE[8];
#pragma unroll
    for (int i = 0; i < 8; ++i) { accH[i] = (f32x4){0.f,0.f,0.f,0.f}; accE[i] = (f32x4){0.f,0.f,0.f,0.f}; }
    float p1 = 0.f, p2 = 0.f, p3 = 0.f, p4 = 0.f;
    // ---- node part: K=256 ----
    for (int k0 = 0; k0 < 256; k0 += 32) {
        int kb = k0 + kg * 8;
        f32x4v alo = __builtin_nontemporal_load(reinterpret_cast<const f32x4v*>(ArowN + kb));
        f32x4v ahi = __builtin_nontemporal_load(reinterpret_cast<const f32x4v*>(ArowN + kb + 4));
        union { unsigned u[4]; bf16x8 v; } af;
        af.u[0] = bf16pair(alo.x, alo.y);
        af.u[1] = bf16pair(alo.z, alo.w);
        af.u[2] = bf16pair(ahi.x, ahi.y);
        af.u[3] = bf16pair(ahi.z, ahi.w);
        {
            float4 wl = *reinterpret_cast<const float4*>(w1 + kb);
            float4 wh = *reinterpret_cast<const float4*>(w1 + kb + 4);
            p1 += alo.x*wl.x + alo.y*wl.y + alo.z*wl.z + alo.w*wl.w
                + ahi.x*wh.x + ahi.y*wh.y + ahi.z*wh.z + ahi.w*wh.w;
        }
        {
            float4 wl = *reinterpret_cast<const float4*>(w2 + kb);
            float4 wh = *reinterpret_cast<const float4*>(w2 + kb + 4);
            p2 += alo.x*wl.x + alo.y*wl.y + alo.z*wl.z + alo.w*wl.w
                + ahi.x*wh.x + ahi.y*wh.y + ahi.z*wh.z + ahi.w*wh.w;
        }
        {
            float4 wl = *reinterpret_cast<const float4*>(w3 + kb);
            float4 wh = *reinterpret_cast<const float4*>(w3 + kb + 4);
            p3 += alo.x*wl.x + alo.y*wl.y + alo.z*wl.z + alo.w*wl.w
                + ahi.x*wh.x + ahi.y*wh.y + ahi.z*wh.z + ahi.w*wh.w;
        }
#pragma unroll
        for (int nt = 0; nt < 8; ++nt) {
            union { unsigned u[4]; bf16x8 v; } bf;
            const unsigned* bp = reinterpret_cast<const unsigned*>(WtN + (size_t)(rl + 16*nt) * 256 + kb);
            bf.u[0] = bp[0]; bf.u[1] = bp[1]; bf.u[2] = bp[2]; bf.u[3] = bp[3];
            accH[nt] = __builtin_amdgcn_mfma_f32_16x16x32_bf16(af.v, bf.v, accH[nt], 0, 0, 0);
        }
    }
    // ---- edge part: K=128 ----
    for (int k0 = 0; k0 < 128; k0 += 32) {
        int kb = k0 + kg * 8;
        f32x4v alo = __builtin_nontemporal_load(reinterpret_cast<const f32x4v*>(ArowE + kb));
        f32x4v ahi = __builtin_nontemporal_load(reinterpret_cast<const f32x4v*>(ArowE + kb + 4));
        union { unsigned u[4]; bf16x8 v; } af;
        af.u[0] = bf16pair(alo.x, alo.y);
        af.u[1] = bf16pair(alo.z, alo.w);
        af.u[2] = bf16pair(ahi.x, ahi.y);
        af.u[3] = bf16pair(ahi.z, ahi.w);
        {
            float4 wl = *reinterpret_cast<const float4*>(w4 + kb);
            float4 wh = *reinterpret_cast<const float4*>(w4 + kb + 4);
            p4 += alo.x*wl.x + alo.y*wl.y + alo.z*wl.z + alo.w*wl.w
                + ahi.x*wh.x + ahi.y*wh.y + ahi.z*wh.z + ahi.w*wh.w;
        }
#pragma unroll
        for (int nt = 0; nt < 8; ++nt) {
            union { unsigned u[4]; bf16x8 v; } bf;
            const unsigned* bp = reinterpret_cast<const unsigned*>(WtE + (size_t)(rl + 16*nt) * 128 + kb);
            bf.u[0] = bp[0]; bf.u[1] = bp[1]; bf.u[2] = bp[2]; bf.u[3] = bp[3];
            accE[nt] = __builtin_amdgcn_mfma_f32_16x16x32_bf16(af.v, bf.v, accE[nt], 0, 0, 0);
        }
    }
    // fused scalar outputs
    p1 += __shfl_xor(p1, 16); p1 += __shfl_xor(p1, 32);
    p2 += __shfl_xor(p2, 16); p2 += __shfl_xor(p2, 32);
    p3 += __shfl_xor(p3, 16); p3 += __shfl_xor(p3, 32);
    p4 += __shfl_xor(p4, 16); p4 += __shfl_xor(p4, 32);
    if (l < 16 && gr < M) { s1[gr] = p1; s2[gr] = p2; t1[gr] = p3; t2e[gr] = p4; }
    // epilogue: full uint2 (h-pair, e-pair) writes
#pragma unroll
    for (int nt = 0; nt < 8; ++nt) {
#pragma unroll
        for (int reg = 0; reg < 4; ++reg) {
            float hm = accH[nt][reg];
            float ho = __shfl_xor(hm, 1);
            float em = accE[nt][reg];
            float eo = __shfl_xor(em, 1);
            int orow = wrow0 + kg * 4 + reg;
            if (orow < M) {
                int col = rl + 16 * nt;
                if (!(l & 1)) {
                    if (reg < 2) {
                        uint2 wv2 = { bf16pair(hm, ho), bf16pair(em, eo) };
                        *reinterpret_cast<uint2*>(hevu + (size_t)orow * 128 + col) = wv2;
                    }
                } else {
                    if (reg >= 2) {
                        uint2 wv2 = { bf16pair(ho, hm), bf16pair(eo, em) };
                        *reinterpret_cast<uint2*>(hevu + (size_t)orow * 128 + (col - 1)) = wv2;
                    }
                }
            }
        }
    }
}

// ---------------- per-edge scalar t2e for rows [NN, EE) ----------------
__global__ void edge_scalar_tail(const float* __restrict__ EF, const float* __restrict__ w,
                                 float* __restrict__ t2e) {
    int wave = NN + (int)((blockIdx.x * (size_t)blockDim.x + threadIdx.x) >> 6);
    int lane = threadIdx.x & 63;
    if (wave >= EE) return;
    f32x2v v = __builtin_nontemporal_load(reinterpret_cast<const f32x2v*>(EF + (size_t)wave * 128 + lane * 2));
    float a = v.x * w[lane * 2] + v.y * w[lane * 2 + 1];
    for (int off = 32; off; off >>= 1) a += __shfl_down(a, off);
    if (lane == 0) t2e[wave] = a;
}

// ---------------- attention: 1 packed u64 atomic + direct static-bucket meta scatter ----------------
// meta[s*CAP + rank] = { d_bits, i_bits, na, ea }
__global__ void attention(const int* __restrict__ edges, const float* __restrict__ s1,
                          const float* __restrict__ s2, const float* __restrict__ t1,
                          const float* __restrict__ t2e, unsigned long long* __restrict__ hist,
                          float4* __restrict__ meta) {
    int i = blockIdx.x * blockDim.x + threadIdx.x;
    if (i >= 2 * EE) return;
    int s, d, j;
    if (i < EE) { j = i; int2 p = *reinterpret_cast<const int2*>(edges + 2 * j); s = p.x; d = p.y; }
    else        { j = i - EE; int2 p = *reinterpret_cast<const int2*>(edges + 2 * j); s = p.y; d = p.x; }
    float xn = s1[s] + s2[d];
    xn = xn >= 0.f ? xn : 0.2f * xn;
    xn = fminf(fmaxf(xn, -2.f), 2.f);
    float na = __expf(xn);
    float xe = t1[s] + t2e[j];
    xe = xe >= 0.f ? xe : 0.2f * xe;
    xe = fminf(fmaxf(xe, -2.f), 2.f);
    float ea = __expf(xe);
    unsigned qn = __float2uint_rn(na * QSCALE);
    unsigned qe = __float2uint_rn(ea * QSCALE);
    unsigned long long pk = (1ULL << 56) | ((unsigned long long)qn << 28) | (unsigned long long)qe;
    unsigned long long old = atomicAdd(&hist[s], pk);
    int rank = (int)(old >> 56) & (CAP - 1);
    meta[(size_t)s * CAP + rank] = make_float4(__int_as_float(d), __int_as_float(i), na, ea);
}

// ---------------- unpack hist + per-scan-chunk count sums ----------------
__global__ void reduce_unpack(const unsigned long long* __restrict__ hist, float* __restrict__ nsum,
                              float* __restrict__ esum, int* __restrict__ counts,
                              int* __restrict__ bsums) {
    __shared__ int sdata[256];
    int b = blockIdx.x, t = threadIdx.x;
    int base = b * SCAN_CHUNK;
    int csum = 0;
    for (int j = 0; j < 8; ++j) {
        int idx = base + j * 256 + t;
        if (idx < NN) {
            unsigned long long h = hist[idx];
            int c = (int)(h >> 56);
            counts[idx] = c;
            nsum[idx] = (float)((h >> 28) & 0x0FFFFFFFULL) * (1.0f / QSCALE);
            esum[idx] = (float)(h & 0x0FFFFFFFULL) * (1.0f / QSCALE);
            csum += c;
        }
    }
    sdata[t] = csum; __syncthreads();
    for (int off = 128; off; off >>= 1) { if (t < off) sdata[t] += sdata[t + off]; __syncthreads(); }
    if (t == 0) bsums[b] = sdata[0];
}

// ---------------- final scan: offsets + position->node map g ----------------
__global__ void scan_final(const int* __restrict__ counts, const int* __restrict__ bsums,
                           int* __restrict__ offsets, int* __restrict__ g) {
    __shared__ int sdata[256];
    int b = blockIdx.x, t = threadIdx.x;
    int base = b * SCAN_CHUNK + t * 8;
    int bbase = 0;
    for (int q = 0; q < b; ++q) bbase += bsums[q];
    int loc[8]; int s = 0;
    for (int j = 0; j < 8; ++j) { int idx = base + j; int v = (idx < NN) ? counts[idx] : 0; loc[j] = v; s += v; }
    sdata[t] = s; __syncthreads();
    for (int off = 1; off < 256; off <<= 1) {
        int v = (t >= off) ? sdata[t - off] : 0;
        __syncthreads();
        sdata[t] += v;
        __syncthreads();
    }
    int run = sdata[t] - s + bbase;
    for (int j = 0; j < 8; ++j) {
        int idx = base + j;
        if (idx < NN) {
            offsets[idx] = run;
            for (int k = 0; k < loc[j]; ++k) g[run + k] = idx;
            run += loc[j];
        }
    }
}

// ---------------- normalize slots in place + variance partials (grid-stride, NO atomics) ----------------
__global__ void normalize_slots(const int* __restrict__ counts, const int* __restrict__ g,
                                const float* __restrict__ nsum, const float* __restrict__ esum,
                                float4* __restrict__ meta, double* __restrict__ partials) {
    double v0 = 0.0, v1 = 0.0, v2 = 0.0, v3 = 0.0;
    const int total = NN * CAP;
    for (int gid = blockIdx.x * blockDim.x + threadIdx.x; gid < total;
         gid += gridDim.x * blockDim.x) {
        int s = gid >> 6, k = gid & (CAP - 1);
        if (k < counts[s]) {
            float4 m = meta[(size_t)s * CAP + k];
            int i = __float_as_int(m.y);
            int lo = g[i];   // positional bucket owner (reference repeat() quirk)
            float nn = m.z / nsum[lo];
            float en = m.w / esum[lo];
            f32x2v upd = { nn, en };
            __builtin_nontemporal_store(upd, reinterpret_cast<f32x2v*>(&meta[(size_t)s * CAP + k].z));
            v0 += (double)nn; v1 += (double)nn * nn;
            v2 += (double)en; v3 += (double)en * en;
        }
    }
    __shared__ double sd[4][4];
    int lane = threadIdx.x & 63, wv = threadIdx.x >> 6;
    for (int off = 32; off; off >>= 1) {
        v0 += __shfl_down(v0, off);
        v1 += __shfl_down(v1, off);
        v2 += __shfl_down(v2, off);
        v3 += __shfl_down(v3, off);
    }
    if (lane == 0) { sd[0][wv] = v0; sd[1][wv] = v1; sd[2][wv] = v2; sd[3][wv] = v3; }
    __syncthreads();
    if (threadIdx.x < 4) {
        double x = sd[threadIdx.x][0] + sd[threadIdx.x][1] + sd[threadIdx.x][2] + sd[threadIdx.x][3];
        partials[(size_t)blockIdx.x * 4 + threadIdx.x] = x;
    }
}

// ---------------- accumulate: wave per node, quarter-wave per edge, 4 edges/trip, depth-2 ----------------
__global__ void accumulate(const float4* __restrict__ meta, const int* __restrict__ counts,
                           const uint4* __restrict__ hev,
                           float* __restrict__ node_out, float* __restrict__ edge_out) {
    int wave = (int)((blockIdx.x * (size_t)blockDim.x + threadIdx.x) >> 6);
    int lane = threadIdx.x & 63;
    if (wave >= NN) return;
    int q = lane >> 4, sl = lane & 15;
    const float4* mb = meta + (size_t)wave * CAP;
    int c = counts[wave];
    float aH[8] = {}, aE[8] = {};
    float4 z = make_float4(0.f, 0.f, 0.f, 0.f);
    uint4 zu = make_uint4(0u, 0u, 0u, 0u);
    int np = (c + 3) >> 2;
    int e0 = q, e1 = 4 + q;
    float4 m0 = (e0 < c) ? mb[e0] : z;
    float4 m1 = (e1 < c) ? mb[e1] : z;
    uint4 v0a = zu, v0b = zu, v1a = zu, v1b = zu;
    if (e0 < c) {
        const uint4* r = hev + (size_t)__float_as_int(m0.x) * 32 + sl * 2;
        v0a = r[0]; v0b = r[1];
    }
    if (e1 < c) {
        const uint4* r = hev + (size_t)__float_as_int(m1.x) * 32 + sl * 2;
        v1a = r[0]; v1b = r[1];
    }
    for (int k = 0; k < np; ++k) {
        int e2 = 4 * (k + 2) + q;
        float4 m2 = (e2 < c) ? mb[e2] : z;
        uint4 v2a = zu, v2b = zu;
        if (e2 < c) {
            const uint4* r = hev + (size_t)__float_as_int(m2.x) * 32 + sl * 2;
            v2a = r[0]; v2b = r[1];
        }
        float nn = m0.z, en = m0.w;
        aH[0] += __uint_as_float(v0a.x << 16) * nn;
        aH[1] += __uint_as_float(v0a.x & 0xFFFF0000u) * nn;
        aE[0] += __uint_as_float(v0a.y << 16) * en;
        aE[1] += __uint_as_float(v0a.y & 0xFFFF0000u) * en;
        aH[2] += __uint_as_float(v0a.z << 16) * nn;
        aH[3] += __uint_as_float(v0a.z & 0xFFFF0000u) * nn;
        aE[2] += __uint_as_float(v0a.w << 16) * en;
        aE[3] += __uint_as_float(v0a.w & 0xFFFF0000u) * en;
        aH[4] += __uint_as_float(v0b.x << 16) * nn;
        aH[5] += __uint_as_float(v0b.x & 0xFFFF0000u) * nn;
        aE[4] += __uint_as_float(v0b.y << 16) * en;
        aE[5] += __uint_as_float(v0b.y & 0xFFFF0000u) * en;
        aH[6] += __uint_as_float(v0b.z << 16) * nn;
        aH[7] += __uint_as_float(v0b.z & 0xFFFF0000u) * nn;
        aE[6] += __uint_as_float(v0b.w << 16) * en;
        aE[7] += __uint_as_float(v0b.w & 0xFFFF0000u) * en;
        m0 = m1; m1 = m2;
        v0a = v1a; v0b = v1b; v1a = v2a; v1b = v2b;
    }
#pragma unroll
    for (int x = 0; x < 8; ++x) {
        aH[x] += __shfl_xor(aH[x], 16); aH[x] += __shfl_xor(aH[x], 32);
        aE[x] += __shfl_xor(aE[x], 16); aE[x] += __shfl_xor(aE[x], 32);
    }
    if (q == 0) {
        f32x4v h0 = { aH[0], aH[1], aH[2], aH[3] };
        f32x4v h1 = { aH[4], aH[5], aH[6], aH[7] };
        f32x4v e0v = { aE[0], aE[1], aE[2], aE[3] };
        f32x4v e1v = { aE[4], aE[5], aE[6], aE[7] };
        __builtin_nontemporal_store(h0, reinterpret_cast<f32x4v*>(node_out + (size_t)wave * 128 + sl * 8));
        __builtin_nontemporal_store(h1, reinterpret_cast<f32x4v*>(node_out + (size_t)wave * 128 + sl * 8 + 4));
        __builtin_nontemporal_store(e0v, reinterpret_cast<f32x4v*>(edge_out + (size_t)wave * 128 + sl * 8));
        __builtin_nontemporal_store(e1v, reinterpret_cast<f32x4v*>(edge_out + (size_t)wave * 128 + sl * 8 + 4));
    }
}

// ---------------- finalize variance: reduce block partials ----------------
__global__ void finalize_var(const double* __restrict__ partials, float* __restrict__ out_var) {
    __shared__ double sd[4][4];
    int t = threadIdx.x;
    int q = t & 3, chunk = t >> 2;   // 64 chunks per moment
    double x = 0.0;
    for (int b = chunk; b < NVBLK; b += 64) x += partials[(size_t)b * 4 + q];
    int lane = t & 63, wv = t >> 6;
    for (int off = 32; off >= 4; off >>= 1) x += __shfl_xor(x, off);
    if (lane < 4) sd[lane][wv] = x;
    __syncthreads();
    if (t == 0) {
        double a0 = sd[0][0] + sd[0][1] + sd[0][2] + sd[0][3];
        double a1 = sd[1][0] + sd[1][1] + sd[1][2] + sd[1][3];
        double a2 = sd[2][0] + sd[2][1] + sd[2][2] + sd[2][3];
        double a3 = sd[3][0] + sd[3][1] + sd[3][2] + sd[3][3];
        double M = 2.0 * EE;
        out_var[0] = (float)((a1 - a0 * a0 / M) / (M - 1.0));
        out_var[1] = (float)((a3 - a2 * a2 / M) / (M - 1.0));
    }
}

extern "C" void kernel_launch(void* const* d_in, const int* in_sizes, int n_in,
                              void* d_out, int out_size, void* d_ws, size_t ws_size,
                              hipStream_t stream) {
    const float* node_fts = (const float*)d_in[0];
    const float* edge_fts = (const float*)d_in[1];
    const int*   edges    = (const int*)d_in[2];
    const float* W_node   = (const float*)d_in[3];
    const float* W_edge   = (const float*)d_in[4];
    const float* a_node   = (const float*)d_in[5];
    const float* a_edge   = (const float*)d_in[6];
    float* out = (float*)d_out;

    char* w = (char*)d_ws;
    auto alloc = [&](size_t bytes) -> void* {
        void* p = (void*)w;
        w += (bytes + 255) & ~(size_t)255;
        return p;
    };
    unsigned* hevu = (unsigned*)alloc((size_t)NN * 512);        // bf16 interleaved h/e rows
    float4* meta = (float4*)alloc((size_t)NN * CAP * 16);       // static buckets (51.2 MB)
    float* s1    = (float*)alloc(NN * 4);
    float* s2    = (float*)alloc(NN * 4);
    float* t1    = (float*)alloc(NN * 4);
    float* t2e   = (float*)alloc(EE * 4);
    int*   offsets = (int*)alloc((NN + 1) * 4);
    int*   g       = (int*)alloc((size_t)2 * EE * 4);
    int*   bsums   = (int*)alloc(64 * 4);
    float* wn_a1 = (float*)alloc(256 * 4);
    float* wn_a2 = (float*)alloc(256 * 4);
    float* wn_e1 = (float*)alloc(256 * 4);
    float* we_a2 = (float*)alloc(128 * 4);
    unsigned short* Wt_node = (unsigned short*)alloc(256 * 128 * 2);
    unsigned short* Wt_edge = (unsigned short*)alloc(128 * 128 * 2);
    float* nsum   = (float*)alloc(NN * 4);
    float* esum   = (float*)alloc(NN * 4);
    int*   counts = (int*)alloc(NN * 4);
    double* partials = (double*)alloc((size_t)NVBLK * 4 * 8);
    unsigned long long* hist = (unsigned long long*)alloc((size_t)NN * 8);

    prep<<<64, 256, 0, stream>>>(W_node, W_edge, a_node, a_edge, wn_a1, wn_a2, wn_e1, we_a2,
                                 Wt_node, Wt_edge, hist);

    const int gemm_grid = (NN + 63) / 64;  // 782
    gemm_fused<<<gemm_grid, 256, 0, stream>>>(node_fts, edge_fts, Wt_node, Wt_edge,
                                              wn_a1, wn_a2, wn_e1, we_a2,
                                              hevu, s1, s2, t1, t2e, NN);

    edge_scalar_tail<<<((EE - NN) + 3) / 4, 256, 0, stream>>>(edge_fts, we_a2, t2e);

    attention<<<(2 * EE + 255) / 256, 256, 0, stream>>>(edges, s1, s2, t1, t2e, hist, meta);

    const int nscan = (NN + SCAN_CHUNK - 1) / SCAN_CHUNK;  // 25
    reduce_unpack<<<nscan, 256, 0, stream>>>(hist, nsum, esum, counts, bsums);
    scan_final<<<nscan, 256, 0, stream>>>(counts, bsums, offsets, g);

    normalize_slots<<<NVBLK, 256, 0, stream>>>(counts, g, nsum, esum, meta, partials);

    accumulate<<<(NN + 3) / 4, 256, 0, stream>>>(meta, counts, (const uint4*)hevu,
                                                 out, out + (size_t)NN * 128);

    finalize_var<<<1, 256, 0, stream>>>(partials, out + (size_t)2 * NN * 128);
}